// Round 14
// baseline (1456.011 us; speedup 1.0000x reference)
//
#include <hip/hip_runtime.h>
#include <hip/hip_bf16.h>
#include <hip/hip_cooperative_groups.h>
#include <math.h>

// Problem constants
constexpr int B  = 16;
constexpr int N  = 8192;     // 2^13
constexpr int E  = 131072;   // 2^17
constexpr int H  = 128;
constexpr int K1 = 4096;
constexpr int K2 = 2048;

constexpr int CHUNKS = 16;
constexpr int NBK    = 16;
constexpr int FCAP   = 12288;

typedef __attribute__((ext_vector_type(8))) short short8;
typedef __attribute__((ext_vector_type(4))) float floatx4;

__device__ __forceinline__ unsigned short f2bf(float f) {
  unsigned u = __float_as_uint(f);
  return (unsigned short)((u + 0x7FFFu + ((u >> 16) & 1u)) >> 16);  // RNE
}
__device__ __forceinline__ float bf2f(unsigned short s) {
  return __uint_as_float(((unsigned)s) << 16);
}
__device__ __forceinline__ int rdlane_i(int v, int l) {
  return __builtin_amdgcn_readlane(v, l);
}
__device__ __forceinline__ float rdlane_f(float v, int l) {
  return __uint_as_float((unsigned)__builtin_amdgcn_readlane((int)__float_as_uint(v), l));
}
__device__ __forceinline__ unsigned cvt_pk_bf16(float a, float b) {
  unsigned r;
  asm("v_cvt_pk_bf16_f32 %0, %1, %2" : "=v"(r) : "v"(a), "v"(b));
  return r;
}

// ---------------------------------------------------------------------------
// CSR build (streaming counting sort) — unchanged
// ---------------------------------------------------------------------------
__global__ __launch_bounds__(256) void hist_pass(const int* __restrict__ ei,
                                                 int* __restrict__ bchist) {
  int blk = blockIdx.x;
  int b = blk >> 4, c = blk & 15;
  __shared__ int h16[NBK];
  if (threadIdx.x < NBK) h16[threadIdx.x] = 0;
  __syncthreads();
  const int* dstp = ei + (size_t)b * 2 * E + E + c * 8192;
  for (int i = 0; i < 32; ++i) {
    int dst = dstp[i * 256 + threadIdx.x];
    atomicAdd(&h16[dst >> 9], 1);
  }
  __syncthreads();
  if (threadIdx.x < NBK) bchist[(blk << 4) + threadIdx.x] = h16[threadIdx.x];
}

__global__ __launch_bounds__(256) void bucket_scan(const int* __restrict__ bchist,
                                                   int* __restrict__ cursor,
                                                   int* __restrict__ bbase,
                                                   const float* __restrict__ W1,
                                                   const float* __restrict__ W2,
                                                   const float* __restrict__ W3,
                                                   unsigned short* __restrict__ Wt,
                                                   float* __restrict__ gacc) {
  if (blockIdx.x >= 16) {
    int w = blockIdx.x - 16;
    const float* W = (w == 0) ? W1 : (w == 1) ? W2 : W3;
    unsigned short* o = Wt + w * 128 * 128;
    for (int i = threadIdx.x; i < 128 * 128; i += 256) {
      int k = i >> 7, n = i & 127;
      o[n * 128 + k] = f2bf(W[i]);
    }
    if (w == 0) {
      for (int i = threadIdx.x; i < B * 128; i += 256) gacc[i] = 0.0f;
    }
    return;
  }
  int b = blockIdx.x;
  int tid = threadIdx.x;
  int c = tid >> 4, k = tid & 15;
  __shared__ int arr[CHUNKS][NBK];
  __shared__ int base[NBK + 1];
  arr[c][k] = bchist[((b * CHUNKS + c) << 4) + k];
  __syncthreads();
  if (tid == 0) {
    int run = 0;
    for (int kk = 0; kk < NBK; ++kk) {
      base[kk] = run;
      int t = 0;
      for (int cc = 0; cc < CHUNKS; ++cc) t += arr[cc][kk];
      run += t;
    }
    base[NBK] = run;
  }
  __syncthreads();
  int pre = 0;
  for (int cc = 0; cc < c; ++cc) pre += arr[cc][k];
  cursor[((b * CHUNKS + c) << 4) + k] = base[k] + pre;
  if (tid < NBK + 1) bbase[b * (NBK + 1) + tid] = base[tid];
}

__global__ __launch_bounds__(256) void bin_scatter(const int* __restrict__ ei,
                                                   const int* __restrict__ cursor,
                                                   unsigned* __restrict__ pbuf) {
  int blk = blockIdx.x;
  int b = blk >> 4, c = blk & 15;
  __shared__ int gcur[NBK], lcnt[NBK], lfill[NBK];
  __shared__ int lbase[NBK + 1];
  __shared__ unsigned sbuf[2048];
  int tid = threadIdx.x;
  if (tid < NBK) gcur[tid] = cursor[(blk << 4) + tid];
  const int* srcp = ei + (size_t)b * 2 * E + c * 8192;
  const int* dstp = srcp + E;
  unsigned* pb = pbuf + (size_t)b * E;

  for (int sc = 0; sc < 4; ++sc) {
    if (tid < NBK) { lcnt[tid] = 0; lfill[tid] = 0; }
    __syncthreads();
    int s8[8], d8[8];
#pragma unroll
    for (int q = 0; q < 8; ++q) {
      int i = sc * 2048 + q * 256 + tid;
      s8[q] = srcp[i]; d8[q] = dstp[i];
      atomicAdd(&lcnt[d8[q] >> 9], 1);
    }
    __syncthreads();
    if (tid == 0) {
      int run = 0;
      for (int k = 0; k < NBK; ++k) { lbase[k] = run; run += lcnt[k]; }
      lbase[NBK] = run;
    }
    __syncthreads();
#pragma unroll
    for (int q = 0; q < 8; ++q) {
      int k = d8[q] >> 9;
      int idx = atomicAdd(&lfill[k], 1);
      sbuf[lbase[k] + idx] = ((unsigned)k << 22) |
                             ((unsigned)(d8[q] & 511) << 13) | (unsigned)s8[q];
    }
    __syncthreads();
    for (int i = tid; i < 2048; i += 256) {
      unsigned pk = sbuf[i];
      int k = (int)(pk >> 22);
      pb[gcur[k] + (i - lbase[k])] = pk;
    }
    __syncthreads();
    if (tid < NBK) gcur[tid] += lcnt[tid];
    __syncthreads();
  }
}

__global__ __launch_bounds__(256) void final_scatter(const unsigned* __restrict__ pbuf,
                                                     const int* __restrict__ bbase,
                                                     int* __restrict__ csr,
                                                     int* __restrict__ offs,
                                                     float* __restrict__ dinv1) {
  int blk = blockIdx.x;
  int b = blk >> 4, k = blk & 15;
  __shared__ int ncnt[512], nbase[512], nfill[512];
  __shared__ int sred[256];
  __shared__ unsigned sbuf[FCAP];
  int tid = threadIdx.x;
  int gbase = bbase[b * (NBK + 1) + k];
  int gend  = bbase[b * (NBK + 1) + k + 1];
  int cnt = gend - gbase;
  const unsigned* pb = pbuf + (size_t)b * E + gbase;

  for (int i = tid; i < 512; i += 256) { ncnt[i] = 0; nfill[i] = 0; }
  __syncthreads();
  for (int i = tid; i < cnt; i += 256) atomicAdd(&ncnt[(pb[i] >> 13) & 511], 1);
  __syncthreads();
  int v0 = ncnt[2 * tid], v1 = ncnt[2 * tid + 1];
  int s = v0 + v1;
  sred[tid] = s;
  __syncthreads();
  for (int off = 1; off < 256; off <<= 1) {
    int x = (tid >= off) ? sred[tid - off] : 0;
    __syncthreads();
    sred[tid] += x;
    __syncthreads();
  }
  int ex = sred[tid] - s;
  nbase[2 * tid] = ex;
  nbase[2 * tid + 1] = ex + v0;
  __syncthreads();
  for (int i = tid; i < 512; i += 256) {
    int node = k * 512 + i;
    offs[b * (N + 1) + node] = gbase + nbase[i];
    dinv1[b * N + node] = rsqrtf((float)ncnt[i] + 1.0f);
  }
  if (k == 15 && tid == 0) offs[b * (N + 1) + N] = E;
  __syncthreads();
  for (int i = tid; i < cnt; i += 256) {
    unsigned pk = pb[i];
    int node = (pk >> 13) & 511;
    int idx = atomicAdd(&nfill[node], 1);
    sbuf[nbase[node] + idx] = pk & 8191u;
  }
  __syncthreads();
  int* co = csr + (size_t)b * E + gbase;
  for (int i = tid; i < cnt; i += 256) co[i] = (int)sbuf[i];
}

// ---------------------------------------------------------------------------
// LAYER-1 FUSED (cooperative): gemm -> sync -> agg -> sync -> score, one
// graph per XCD per phase (2 phases). tmp stays dirty in the producing XCD's
// L2, so agg's row gathers are L2 hits instead of L3/fabric (~8 TB/s wall).
// h written nontemporal to avoid evicting tmp; x read nontemporal.
// ---------------------------------------------------------------------------
__global__ __launch_bounds__(256, 8) void layer1_fused(
    const float* __restrict__ x, const unsigned short* __restrict__ Wt,
    unsigned short* __restrict__ tmp, const float* __restrict__ dinv,
    const int* __restrict__ offs, const int* __restrict__ csr,
    const float* __restrict__ bias, unsigned short* __restrict__ hout,
    const float* __restrict__ wrel, const float* __restrict__ wroot,
    float* __restrict__ rr, float* __restrict__ tt,
    const float* __restrict__ pb, float* __restrict__ score) {
  auto grid = cooperative_groups::this_grid();
  int blk = blockIdx.x;                 // 2048
  int xcd = blk & 7;
  int local = blk >> 3;                 // 0..255
  int tid = threadIdx.x;
  int wv = tid >> 6, lane = tid & 63;
  int l15 = lane & 15, lg = lane >> 4;

  for (int p = 0; p < 2; ++p) {
    int g = xcd + 8 * p;

    // ================= GEMM: 32 rows/block (waves 0,1: 16 rows each) ======
    if (wv < 2) {
      int row0 = local * 32 + wv * 16;
      const float* xg = x + ((size_t)g * N + row0) * 128;
      unsigned short* tg = tmp + ((size_t)g * N) * 128;

      short8 afrag[4];
#pragma unroll
      for (int c = 0; c < 4; ++c) {
        const float* pp = xg + l15 * 128 + c * 32 + lg * 8;
        floatx4 v0 = __builtin_nontemporal_load((const floatx4*)pp);
        floatx4 v1 = __builtin_nontemporal_load((const floatx4*)(pp + 4));
        short8 a;
        a[0] = (short)f2bf(v0.x); a[1] = (short)f2bf(v0.y);
        a[2] = (short)f2bf(v0.z); a[3] = (short)f2bf(v0.w);
        a[4] = (short)f2bf(v1.x); a[5] = (short)f2bf(v1.y);
        a[6] = (short)f2bf(v1.z); a[7] = (short)f2bf(v1.w);
        afrag[c] = a;
      }
      float4 fs4 = *(const float4*)(dinv + g * N + row0 + lg * 4);
      float fsr[4] = {fs4.x, fs4.y, fs4.z, fs4.w};

#pragma unroll
      for (int t = 0; t < 8; ++t) {
        int col = t * 16 + l15;
        floatx4 acc = {0.f, 0.f, 0.f, 0.f};
#pragma unroll
        for (int c = 0; c < 4; ++c) {
          short8 bfrag = *(const short8*)(Wt + col * 128 + c * 32 + lg * 8);
          acc = __builtin_amdgcn_mfma_f32_16x16x32_bf16(afrag[c], bfrag, acc, 0, 0, 0);
        }
#pragma unroll
        for (int r = 0; r < 4; ++r)
          tg[(size_t)(row0 + lg * 4 + r) * 128 + col] = f2bf(acc[r] * fsr[r]);
      }
    }
    grid.sync();

    // ================= AGG: 32 nodes/block, 8 per wave ====================
    {
      const unsigned* tmpb = (const unsigned*)tmp + (((size_t)g << 13) << 6);
      const int* cs = csr + (size_t)g * E;
      for (int it = 0; it < 8; ++it) {
        int n = local * 32 + wv * 8 + it;
        int wid = g * N + n;
        float dv = rdlane_f(dinv[wid], 0);
        unsigned* hrow = (unsigned*)hout + (size_t)wid * 64;

        float2 accA, accB;
        {
          unsigned u = tmpb[((unsigned)n << 6) + lane];
          accA.x = __uint_as_float(u << 16);
          accA.y = __uint_as_float(u & 0xFFFF0000u);
          accB.x = 0.0f; accB.y = 0.0f;
        }
        int nbase = g * (N + 1) + n;
        int o0 = __builtin_amdgcn_readfirstlane(offs[nbase]);
        int d  = __builtin_amdgcn_readfirstlane(offs[nbase + 1]) - o0;

        for (int base = 0; base < d; base += 64) {
          int nv = d - base; if (nv > 64) nv = 64;
          int sl = (lane < nv) ? cs[o0 + base + lane] : 0;
          int nfull = nv >> 4;
          for (int t = 0; t < nfull; ++t) {
            int i0 = t << 4;
            unsigned uu[16];
#pragma unroll
            for (int q = 0; q < 16; ++q) {
              int sq = rdlane_i(sl, i0 + q);
              uu[q] = tmpb[((unsigned)sq << 6) + lane];
            }
#pragma unroll
            for (int q = 0; q < 16; ++q) {
              float lo = __uint_as_float(uu[q] << 16);
              float hi = __uint_as_float(uu[q] & 0xFFFF0000u);
              if (q & 1) { accB.x += lo; accB.y += hi; }
              else       { accA.x += lo; accA.y += hi; }
            }
          }
          int rem = nv & 15;
          if (rem) {
            int i0 = nfull << 4;
            unsigned uu[16];
#pragma unroll
            for (int q = 0; q < 16; ++q) {
              int idx = i0 + q;
              int sq = rdlane_i(sl, idx < nv ? idx : 0);
              unsigned v = tmpb[((unsigned)sq << 6) + lane];
              uu[q] = (idx < nv) ? v : 0u;
            }
#pragma unroll
            for (int q = 0; q < 16; ++q) {
              float lo = __uint_as_float(uu[q] << 16);
              float hi = __uint_as_float(uu[q] & 0xFFFF0000u);
              if (q & 1) { accB.x += lo; accB.y += hi; }
              else       { accA.x += lo; accA.y += hi; }
            }
          }
        }

        float2 acc = {accA.x + accB.x, accA.y + accB.y};
        const float2 bb = *(const float2*)(bias + lane * 2);
        float2 outv;
        outv.x = fmaxf(dv * acc.x + bb.x, 0.0f);
        outv.y = fmaxf(dv * acc.y + bb.y, 0.0f);
        __builtin_nontemporal_store(cvt_pk_bf16(outv.x, outv.y), hrow + lane);

        const float2 wr = *(const float2*)(wrel + lane * 2);
        const float2 wo = *(const float2*)(wroot + lane * 2);
        float pr = outv.x * wr.x + outv.y * wr.y;
        float pt = outv.x * wo.x + outv.y * wo.y;
#pragma unroll
        for (int dd = 32; dd > 0; dd >>= 1) {
          pr += __shfl_down(pr, dd);
          pt += __shfl_down(pt, dd);
        }
        if (lane == 0) { rr[wid] = pr; tt[wid] = pt; }
      }
    }
    grid.sync();

    // ================= SCORE: 32 nodes/block, 16 lanes/node ===============
    {
      int grp = tid >> 4, gl = tid & 15;
      const int* cs = csr + (size_t)g * E;
      const float* rb = rr + g * N;
      for (int it = 0; it < 2; ++it) {
        int n = local * 32 + it * 16 + grp;
        int nid = g * N + n;
        int o0 = offs[g * (N + 1) + n], o1 = offs[g * (N + 1) + n + 1];
        float s = 0.0f;
        for (int base = o0; base < o1; base += 16)
          if (base + gl < o1) s += rb[cs[base + gl]];
#pragma unroll
        for (int dd = 8; dd > 0; dd >>= 1) s += __shfl_xor(s, dd, 16);
        if (gl == 0) score[nid] = s + tt[nid] + pb[0];
      }
    }
    // no sync needed before next phase's gemm (disjoint regions)
  }
}

// ---------------------------------------------------------------------------
// GEMM layers 2/3: LIVE rows only via per-graph index list.
// ---------------------------------------------------------------------------
template <int LGB>
__global__ __launch_bounds__(256) void gemm_idx(const unsigned short* __restrict__ Ab,
                                                const unsigned short* __restrict__ Wt,
                                                unsigned short* __restrict__ Cb,
                                                const float* __restrict__ fscale,
                                                const float* __restrict__ dscale,
                                                const int* __restrict__ idxl) {
  __shared__ unsigned short Wsh[128 * 128];
  __shared__ int ridx[128];
  int tid  = threadIdx.x;
  int lane = tid & 63;
  int l15  = lane & 15, lg = lane >> 4;
  int b    = blockIdx.x >> LGB;
  int lblk = blockIdx.x & ((1 << LGB) - 1);
  int woff = (tid >> 6) * 32;

  if (tid < 128) ridx[tid] = idxl[b * N + lblk * 128 + tid];
#pragma unroll
  for (int i = 0; i < 8; ++i) {
    int idx = tid + i * 256;
    int row = idx >> 4, s = idx & 15;
    short8 v = *(const short8*)(Wt + idx * 8);
    *(short8*)(Wsh + row * 128 + (s ^ (row & 15)) * 8) = v;
  }
  __syncthreads();

  const unsigned short* Ag = Ab + (size_t)b * N * 128;
  unsigned short* Cg = Cb + (size_t)b * N * 128;
  const float* fsb = fscale + b * N;
  const float* dsb = dscale + b * N;

  short8 afrag[2][4];
#pragma unroll
  for (int rg = 0; rg < 2; ++rg) {
    int arow = ridx[woff + rg * 16 + l15];
#pragma unroll
    for (int c = 0; c < 4; ++c)
      afrag[rg][c] = *(const short8*)(Ag + (size_t)arow * 128 + c * 32 + lg * 8);
  }

  int orow[2][4]; float fsr[2][4];
#pragma unroll
  for (int rg = 0; rg < 2; ++rg)
#pragma unroll
    for (int r = 0; r < 4; ++r) {
      int o = ridx[woff + rg * 16 + lg * 4 + r];
      orow[rg][r] = o;
      fsr[rg][r] = fsb[o] * dsb[o];
    }

#pragma unroll
  for (int t = 0; t < 8; ++t) {
    int col = t * 16 + l15;
    short8 bfrag[4];
#pragma unroll
    for (int c = 0; c < 4; ++c)
      bfrag[c] = *(const short8*)(Wsh + col * 128 + ((c * 4 + lg) ^ (col & 15)) * 8);

    floatx4 acc0 = {0.f, 0.f, 0.f, 0.f};
    floatx4 acc1 = {0.f, 0.f, 0.f, 0.f};
#pragma unroll
    for (int c = 0; c < 4; ++c) {
      acc0 = __builtin_amdgcn_mfma_f32_16x16x32_bf16(afrag[0][c], bfrag[c], acc0, 0, 0, 0);
      acc1 = __builtin_amdgcn_mfma_f32_16x16x32_bf16(afrag[1][c], bfrag[c], acc1, 0, 0, 0);
    }
#pragma unroll
    for (int r = 0; r < 4; ++r) {
      Cg[(size_t)orow[0][r] * 128 + col] = f2bf(acc0[r] * fsr[0][r]);
      Cg[(size_t)orow[1][r] * 128 + col] = f2bf(acc1[r] * fsr[1][r]);
    }
  }
}

// ---------------------------------------------------------------------------
// GCN aggregation layers 2/3 (live index list)
// ---------------------------------------------------------------------------
template <int LOGPG, bool FUSE_RO>
__global__ __launch_bounds__(256) void gcn_agg_idx(
    const unsigned* __restrict__ tmp, const float* __restrict__ dinv,
    const int* __restrict__ offs, const int* __restrict__ ecnt,
    const int* __restrict__ csr, const float* __restrict__ bias,
    unsigned* __restrict__ hout, const float* __restrict__ wrel,
    const float* __restrict__ wroot, float* __restrict__ rr,
    float* __restrict__ tt, const int* __restrict__ idxl,
    float* __restrict__ gacc) {
  __shared__ float racc[128];
  int blk = blockIdx.x;
  int xcd = blk & 7;
  int j   = blk >> 3;
  int b   = xcd + 8 * (j >> LOGPG);
  int i   = (j & ((1 << LOGPG) - 1)) * 4 + (threadIdx.x >> 6);
  int lane = threadIdx.x & 63;

  if (FUSE_RO) {
    if (threadIdx.x < 128) racc[threadIdx.x] = 0.0f;
    __syncthreads();
  }

  int n = __builtin_amdgcn_readfirstlane(idxl[b * N + i]);
  int wid = b * N + n;
  float dv = rdlane_f(dinv[wid], 0);

  const unsigned* tmpb = tmp + (((size_t)b << 13) << 6);
  const int* cs = csr + (size_t)b * E;

  float2 accA, accB;
  {
    unsigned u = tmpb[((unsigned)n << 6) + lane];
    accA.x = __uint_as_float(u << 16);
    accA.y = __uint_as_float(u & 0xFFFF0000u);
    accB.x = 0.0f; accB.y = 0.0f;
  }

  int o0 = __builtin_amdgcn_readfirstlane(offs[b * (N + 1) + n]);
  int d  = __builtin_amdgcn_readfirstlane(ecnt[wid]);

  for (int base = 0; base < d; base += 64) {
    int nv = d - base; if (nv > 64) nv = 64;
    int sl = (lane < nv) ? cs[o0 + base + lane] : 0;
    int nfull = nv >> 4;
    for (int t = 0; t < nfull; ++t) {
      int i0 = t << 4;
      unsigned uu[16];
#pragma unroll
      for (int q = 0; q < 16; ++q) {
        int sq = rdlane_i(sl, i0 + q);
        uu[q] = tmpb[((unsigned)sq << 6) + lane];
      }
#pragma unroll
      for (int q = 0; q < 16; ++q) {
        float lo = __uint_as_float(uu[q] << 16);
        float hi = __uint_as_float(uu[q] & 0xFFFF0000u);
        if (q & 1) { accB.x += lo; accB.y += hi; }
        else       { accA.x += lo; accA.y += hi; }
      }
    }
    int rem = nv & 15;
    if (rem) {
      int i0 = nfull << 4;
      unsigned uu[16];
#pragma unroll
      for (int q = 0; q < 16; ++q) {
        int idx = i0 + q;
        int sq = rdlane_i(sl, idx < nv ? idx : 0);
        unsigned v = tmpb[((unsigned)sq << 6) + lane];
        uu[q] = (idx < nv) ? v : 0u;
      }
#pragma unroll
      for (int q = 0; q < 16; ++q) {
        float lo = __uint_as_float(uu[q] << 16);
        float hi = __uint_as_float(uu[q] & 0xFFFF0000u);
        if (q & 1) { accB.x += lo; accB.y += hi; }
        else       { accA.x += lo; accA.y += hi; }
      }
    }
  }

  float2 acc = {accA.x + accB.x, accA.y + accB.y};
  const float2 bb = *(const float2*)(bias + lane * 2);
  float2 outv;
  outv.x = fmaxf(dv * acc.x + bb.x, 0.0f);
  outv.y = fmaxf(dv * acc.y + bb.y, 0.0f);

  if (!FUSE_RO) {
    unsigned* hrow = hout + (size_t)wid * 64;
    hrow[lane] = cvt_pk_bf16(outv.x, outv.y);
    const float2 wr = *(const float2*)(wrel + lane * 2);
    const float2 wo = *(const float2*)(wroot + lane * 2);
    float pr = outv.x * wr.x + outv.y * wr.y;
    float pt = outv.x * wo.x + outv.y * wo.y;
#pragma unroll
    for (int dd = 32; dd > 0; dd >>= 1) {
      pr += __shfl_down(pr, dd);
      pt += __shfl_down(pt, dd);
    }
    if (lane == 0) { rr[wid] = pr; tt[wid] = pt; }
  } else {
    atomicAdd(&racc[lane * 2],     outv.x);
    atomicAdd(&racc[lane * 2 + 1], outv.y);
    __syncthreads();
    if (threadIdx.x < 128) atomicAdd(&gacc[b * 128 + threadIdx.x], racc[threadIdx.x]);
  }
}

// ---------------------------------------------------------------------------
// compact (live nodes only, via index list)
// ---------------------------------------------------------------------------
template <int LOGK>
__global__ __launch_bounds__(256) void compact_idx(
    const int* __restrict__ idxl, const float* __restrict__ mask,
    const int* __restrict__ offs, const int* __restrict__ ecnt_in,
    int* __restrict__ csr, int* __restrict__ ecnt_out,
    float* __restrict__ dinv_out) {
  int ws = blockIdx.x * 4 + (threadIdx.x >> 6);
  int b = ws >> LOGK;
  int i = ws & ((1 << LOGK) - 1);
  int lane = threadIdx.x & 63;
  int n = __builtin_amdgcn_readfirstlane(idxl[b * N + i]);
  int wid = b * N + n;
  int nb = b * (N + 1) + n;
  int o0 = __builtin_amdgcn_readfirstlane(offs[nb]);
  int din = (ecnt_in != nullptr)
                ? __builtin_amdgcn_readfirstlane(ecnt_in[wid])
                : __builtin_amdgcn_readfirstlane(offs[nb + 1]) - o0;
  int* cs = csr + (size_t)b * E;
  const float* mb = mask + b * N;
  int wpos = o0;
  for (int base = 0; base < din; base += 64) {
    int nv = din - base; if (nv > 64) nv = 64;
    int s = (lane < nv) ? cs[o0 + base + lane] : 0;
    bool alive = (lane < nv) && (mb[s] > 0.0f);
    unsigned long long bal = __ballot(alive);
    int idx = __popcll(bal & ((1ull << lane) - 1ull));
    if (alive) cs[wpos + idx] = s;
    wpos += __popcll(bal);
  }
  if (lane == 0) {
    int total = wpos - o0;
    ecnt_out[wid] = total;
    dinv_out[wid] = rsqrtf((float)total + 1.0f);
  }
}

// ---------------------------------------------------------------------------
// pool score layer 2 (idx-restricted)
// ---------------------------------------------------------------------------
__global__ __launch_bounds__(256) void score_idx(const float* __restrict__ r,
                                                 const float* __restrict__ t,
                                                 const float* __restrict__ pb,
                                                 const int* __restrict__ offs,
                                                 const int* __restrict__ ecnt,
                                                 const int* __restrict__ csr,
                                                 float* __restrict__ score,
                                                 const int* __restrict__ idxl) {
  int grp = threadIdx.x >> 4;
  int gl  = threadIdx.x & 15;
  int ws  = blockIdx.x * 16 + grp;
  int b = ws >> 12;
  int i = ws & (K1 - 1);
  int n = idxl[b * N + i];
  int nid = b * N + n;
  int o0 = offs[b * (N + 1) + n];
  int d  = ecnt[nid];
  const int* cs = csr + (size_t)b * E;
  const float* rb = r + b * N;
  float s = 0.0f;
  for (int base = 0; base < d; base += 16)
    if (base + gl < d) s += rb[cs[o0 + base + gl]];
#pragma unroll
  for (int dd = 8; dd > 0; dd >>= 1) s += __shfl_xor(s, dd, 16);
  if (gl == 0) score[nid] = s + t[nid] + pb[0];
}

// ---------------------------------------------------------------------------
// top-k via radix select + compacted index emission
// ---------------------------------------------------------------------------
__device__ __forceinline__ unsigned fkey(float s, float m) {
  if (m <= 0.0f) return 0u;
  unsigned u = __float_as_uint(s);
  return (u & 0x80000000u) ? ~u : (u | 0x80000000u);
}

__global__ __launch_bounds__(1024) void topk_kernel(const float* __restrict__ score,
                                                    const float* __restrict__ mkin,
                                                    float* __restrict__ mkout,
                                                    float* __restrict__ fscale,
                                                    int* __restrict__ idxo,
                                                    int k) {
  int b = blockIdx.x, tid = threadIdx.x;
  const float* sc = score + b * N;
  float* mk = mkout + b * N;
  float* fs = fscale + b * N;
  __shared__ unsigned keyb[N];
  __shared__ int hist[256];
  __shared__ unsigned sh_prefix;
  __shared__ int sh_kneed;
  __shared__ int wsum[16], wexc[16];

  for (int i = tid; i < N; i += 1024) {
    float m = (mkin == nullptr) ? 1.0f : mkin[b * N + i];
    keyb[i] = fkey(sc[i], m);
  }
  __syncthreads();

  unsigned prefix = 0, hm = 0;
  int kneed = k;
  for (int shift = 24; shift >= 0; shift -= 8) {
    if (tid < 256) hist[tid] = 0;
    __syncthreads();
    for (int i = tid; i < N; i += 1024) {
      unsigned key = keyb[i];
      if ((key & hm) == prefix) atomicAdd(&hist[(key >> shift) & 255], 1);
    }
    __syncthreads();
    if (tid < 64) {
      int b4[4]; int s = 0;
#pragma unroll
      for (int j = 0; j < 4; ++j) { b4[j] = hist[tid * 4 + j]; s += b4[j]; }
      int suf = s;
#pragma unroll
      for (int o = 1; o < 64; o <<= 1) {
        int v = __shfl_down(suf, o);
        if (tid + o < 64) suf += v;
      }
      int run = suf - s;
      for (int j = 3; j >= 0; --j) {
        if (run < kneed && run + b4[j] >= kneed) {
          sh_prefix = prefix | ((unsigned)(tid * 4 + j) << shift);
          sh_kneed = kneed - run;
        }
        run += b4[j];
      }
    }
    __syncthreads();
    prefix = sh_prefix;
    kneed = sh_kneed;
    hm |= (0xFFu << shift);
  }

  unsigned T = prefix;
  int base = tid * 8;
  unsigned keys[8];
  int eqf[8];
  int cnt = 0;
#pragma unroll
  for (int q = 0; q < 8; ++q) {
    keys[q] = keyb[base + q];
    eqf[q] = (keys[q] == T) ? 1 : 0;
    cnt += eqf[q];
  }
  int inc = cnt;
  int wl = tid & 63;
#pragma unroll
  for (int o = 1; o < 64; o <<= 1) {
    int v = __shfl_up(inc, o);
    if (wl >= o) inc += v;
  }
  if (wl == 63) wsum[tid >> 6] = inc;
  __syncthreads();
  if (tid < 16) {
    int v = wsum[tid];
    int in = v;
#pragma unroll
    for (int o = 1; o < 16; o <<= 1) {
      int u = __shfl_up(in, o);
      if (tid >= o) in += u;
    }
    wexc[tid] = in - v;
  }
  __syncthreads();
  int ex = wexc[tid >> 6] + (inc - cnt);
  int scnt = 0; bool selq[8];
#pragma unroll
  for (int q = 0; q < 8; ++q) {
    bool sel = (keys[q] > T) || (eqf[q] && (ex < kneed));
    ex += eqf[q];
    mk[base + q] = sel ? 1.0f : 0.0f;
    fs[base + q] = sel ? tanhf(sc[base + q]) : 0.0f;
    selq[q] = sel; scnt += sel;
  }
  int inc2 = scnt;
#pragma unroll
  for (int o = 1; o < 64; o <<= 1) {
    int v = __shfl_up(inc2, o);
    if (wl >= o) inc2 += v;
  }
  __syncthreads();
  if (wl == 63) wsum[tid >> 6] = inc2;
  __syncthreads();
  if (tid < 16) {
    int v = wsum[tid];
    int in = v;
#pragma unroll
    for (int o = 1; o < 16; o <<= 1) {
      int u = __shfl_up(in, o);
      if (tid >= o) in += u;
    }
    wexc[tid] = in - v;
  }
  __syncthreads();
  int spos = wexc[tid >> 6] + (inc2 - scnt);
  int* io = idxo + b * N;
#pragma unroll
  for (int q = 0; q < 8; ++q)
    if (selq[q]) io[spos++] = base + q;
}

// ---------------------------------------------------------------------------
// head MLP + log_softmax
// ---------------------------------------------------------------------------
__global__ __launch_bounds__(128) void head(const float* __restrict__ gacc,
                                            const float* __restrict__ l1w,
                                            const float* __restrict__ l1b,
                                            const float* __restrict__ l2w,
                                            const float* __restrict__ l2b,
                                            float* __restrict__ out) {
  int b = blockIdx.x, f = threadIdx.x;
  float g = gacc[b * 128 + f] * (1.0f / (float)K2);
  __shared__ float gs[128], hh[128], lg[10];
  gs[f] = g; __syncthreads();
  float a = l1b[f];
  for (int kk = 0; kk < 128; ++kk) a += gs[kk] * l1w[kk * 128 + f];
  hh[f] = fmaxf(a, 0.0f); __syncthreads();
  if (f < 10) {
    float l = l2b[f];
    for (int j = 0; j < 128; ++j) l += hh[j] * l2w[j * 10 + f];
    lg[f] = l;
  }
  __syncthreads();
  if (f == 0) {
    float m = lg[0];
    for (int c = 1; c < 10; ++c) m = fmaxf(m, lg[c]);
    float s = 0.0f;
    for (int c = 0; c < 10; ++c) s += expf(lg[c] - m);
    float lse = m + logf(s);
    for (int c = 0; c < 10; ++c) out[b * 10 + c] = lg[c] - lse;
  }
}

// ---------------------------------------------------------------------------
extern "C" void kernel_launch(void* const* d_in, const int* in_sizes, int n_in,
                              void* d_out, int out_size, void* d_ws, size_t ws_size,
                              hipStream_t stream) {
  (void)in_sizes; (void)n_in; (void)out_size; (void)ws_size;
  const float* x       = (const float*)d_in[0];
  const int*   ei      = (const int*)d_in[1];
  const float* W1      = (const float*)d_in[2];
  const float* b1      = (const float*)d_in[3];
  const float* p1_wrel = (const float*)d_in[4];
  const float* p1_wroot= (const float*)d_in[5];
  const float* p1_b    = (const float*)d_in[6];
  const float* W2      = (const float*)d_in[7];
  const float* b2      = (const float*)d_in[8];
  const float* p2_wrel = (const float*)d_in[9];
  const float* p2_wroot= (const float*)d_in[10];
  const float* p2_b    = (const float*)d_in[11];
  const float* W3      = (const float*)d_in[12];
  const float* b3      = (const float*)d_in[13];
  const float* l1w     = (const float*)d_in[14];
  const float* l1b     = (const float*)d_in[15];
  const float* l2w     = (const float*)d_in[16];
  const float* l2b     = (const float*)d_in[17];
  float* out = (float*)d_out;

  char* p = (char*)d_ws;
  auto alloc = [&](size_t bytes) {
    char* r = p;
    p += ((bytes + 255) & ~(size_t)255);
    return r;
  };
  unsigned short* h   = (unsigned short*)alloc((size_t)B * N * H * 2);   // bf16
  unsigned short* tmp = (unsigned short*)alloc((size_t)B * N * H * 2);   // bf16
  int*      offs   = (int*)alloc((size_t)B * (N + 1) * 4);
  int*      csr    = (int*)alloc((size_t)B * E * 4);
  unsigned* pbuf   = (unsigned*)alloc((size_t)B * E * 4);
  int*      bchist = (int*)alloc((size_t)B * CHUNKS * NBK * 4);
  int*      cursor = (int*)alloc((size_t)B * CHUNKS * NBK * 4);
  int*      bbase  = (int*)alloc((size_t)B * (NBK + 1) * 4);
  int*      ecnt   = (int*)alloc((size_t)B * N * 4);
  int*      idx1   = (int*)alloc((size_t)B * N * 4);
  int*      idx2   = (int*)alloc((size_t)B * N * 4);
  float* dinv   = (float*)alloc((size_t)B * N * 4);
  float* mask   = (float*)alloc((size_t)B * N * 4);
  float* rr     = (float*)alloc((size_t)B * N * 4);
  float* tt     = (float*)alloc((size_t)B * N * 4);
  float* score  = (float*)alloc((size_t)B * N * 4);
  float* fscale = (float*)alloc((size_t)B * N * 4);
  float* gacc   = (float*)alloc((size_t)B * 128 * 4);
  unsigned short* Wts = (unsigned short*)alloc(3 * 128 * 128 * 2);

  // CSR build + weight prep + gacc zeroing (fused)
  hist_pass<<<B * CHUNKS, 256, 0, stream>>>(ei, bchist);
  bucket_scan<<<19, 256, 0, stream>>>(bchist, cursor, bbase, W1, W2, W3, Wts, gacc);
  bin_scatter<<<B * CHUNKS, 256, 0, stream>>>(ei, cursor, pbuf);
  final_scatter<<<B * NBK, 256, 0, stream>>>(pbuf, bbase, csr, offs, dinv);

  // ---- layer 1 fused (cooperative): gemm + agg + score, XCD-local L2
  {
    const float* xx = x; const unsigned short* wt = Wts;
    unsigned short* tp = tmp; const float* dv = dinv;
    const int* of = offs; const int* cs = csr;
    const float* bb = b1; unsigned short* hh = h;
    const float* wr = p1_wrel; const float* wo = p1_wroot;
    float* r_ = rr; float* t_ = tt;
    const float* pb_ = p1_b; float* sc_ = score;
    void* args[] = {&xx, &wt, &tp, &dv, &of, &cs, &bb, &hh,
                    &wr, &wo, &r_, &t_, &pb_, &sc_};
    (void)hipLaunchCooperativeKernel((const void*)layer1_fused, dim3(2048), dim3(256),
                                     args, 0, stream);
  }
  topk_kernel<<<B, 1024, 0, stream>>>(score, nullptr, mask, fscale, idx1, K1);
  compact_idx<12><<<B * K1 / 4, 256, 0, stream>>>(idx1, mask, offs, nullptr, csr,
                                                  ecnt, dinv);

  // ---- layer 2 + pool 2 (live subgraph via idx1)
  gemm_idx<5><<<B * (K1 / 128), 256, 0, stream>>>(h, Wts + 128 * 128, tmp,
                                                  fscale, dinv, idx1);
  gcn_agg_idx<10, false><<<B * K1 / 4, 256, 0, stream>>>(
      (const unsigned*)tmp, dinv, offs, ecnt, csr, b2, (unsigned*)h,
      p2_wrel, p2_wroot, rr, tt, idx1, nullptr);
  score_idx<<<B * K1 / 16, 256, 0, stream>>>(rr, tt, p2_b, offs, ecnt, csr,
                                             score, idx1);
  topk_kernel<<<B, 1024, 0, stream>>>(score, mask, mask, fscale, idx2, K2);
  compact_idx<11><<<B * K2 / 4, 256, 0, stream>>>(idx2, mask, offs, ecnt, csr,
                                                  ecnt, dinv);

  // ---- layer 3 (live subgraph via idx2; fused readout)
  gemm_idx<4><<<B * (K2 / 128), 256, 0, stream>>>(h, Wts + 2 * 128 * 128, tmp,
                                                  fscale, dinv, idx2);
  gcn_agg_idx<9, true><<<B * K2 / 4, 256, 0, stream>>>(
      (const unsigned*)tmp, dinv, offs, ecnt, csr, b3, nullptr,
      nullptr, nullptr, nullptr, nullptr, idx2, gacc);

  // ---- head
  head<<<B, 128, 0, stream>>>(gacc, l1w, l1b, l2w, l2b, out);
}

// Round 15
// 324.490 us; speedup vs baseline: 4.4871x; 4.4871x over previous
//
#include <hip/hip_runtime.h>
#include <hip/hip_bf16.h>
#include <math.h>

// Problem constants
constexpr int B  = 16;
constexpr int N  = 8192;     // 2^13
constexpr int E  = 131072;   // 2^17
constexpr int H  = 128;
constexpr int K1 = 4096;
constexpr int K2 = 2048;

constexpr int CHUNKS = 16;
constexpr int NBK    = 16;
constexpr int FCAP   = 12288;

typedef __attribute__((ext_vector_type(8))) short short8;
typedef __attribute__((ext_vector_type(4))) float floatx4;

__device__ __forceinline__ unsigned short f2bf(float f) {
  unsigned u = __float_as_uint(f);
  return (unsigned short)((u + 0x7FFFu + ((u >> 16) & 1u)) >> 16);  // RNE
}
__device__ __forceinline__ float bf2f(unsigned short s) {
  return __uint_as_float(((unsigned)s) << 16);
}
__device__ __forceinline__ int rdlane_i(int v, int l) {
  return __builtin_amdgcn_readlane(v, l);
}
__device__ __forceinline__ float rdlane_f(float v, int l) {
  return __uint_as_float((unsigned)__builtin_amdgcn_readlane((int)__float_as_uint(v), l));
}
__device__ __forceinline__ unsigned cvt_pk_bf16(float a, float b) {
  unsigned r;
  asm("v_cvt_pk_bf16_f32 %0, %1, %2" : "=v"(r) : "v"(a), "v"(b));
  return r;
}

// ---------------------------------------------------------------------------
// CSR build (streaming counting sort)
// ---------------------------------------------------------------------------
__global__ __launch_bounds__(256) void hist_pass(const int* __restrict__ ei,
                                                 int* __restrict__ bchist) {
  int blk = blockIdx.x;
  int b = blk >> 4, c = blk & 15;
  __shared__ int h16[NBK];
  if (threadIdx.x < NBK) h16[threadIdx.x] = 0;
  __syncthreads();
  const int* dstp = ei + (size_t)b * 2 * E + E + c * 8192;
  for (int i = 0; i < 32; ++i) {
    int dst = dstp[i * 256 + threadIdx.x];
    atomicAdd(&h16[dst >> 9], 1);
  }
  __syncthreads();
  if (threadIdx.x < NBK) bchist[(blk << 4) + threadIdx.x] = h16[threadIdx.x];
}

__global__ __launch_bounds__(256) void bucket_scan(const int* __restrict__ bchist,
                                                   int* __restrict__ cursor,
                                                   int* __restrict__ bbase,
                                                   const float* __restrict__ W1,
                                                   const float* __restrict__ W2,
                                                   const float* __restrict__ W3,
                                                   unsigned short* __restrict__ Wt,
                                                   float* __restrict__ gacc) {
  if (blockIdx.x >= 16) {
    int w = blockIdx.x - 16;
    const float* W = (w == 0) ? W1 : (w == 1) ? W2 : W3;
    unsigned short* o = Wt + w * 128 * 128;
    for (int i = threadIdx.x; i < 128 * 128; i += 256) {
      int k = i >> 7, n = i & 127;
      o[n * 128 + k] = f2bf(W[i]);
    }
    if (w == 0) {                       // fold gacc zeroing in (saves a memset)
      for (int i = threadIdx.x; i < B * 128; i += 256) gacc[i] = 0.0f;
    }
    return;
  }
  int b = blockIdx.x;
  int tid = threadIdx.x;
  int c = tid >> 4, k = tid & 15;
  __shared__ int arr[CHUNKS][NBK];
  __shared__ int base[NBK + 1];
  arr[c][k] = bchist[((b * CHUNKS + c) << 4) + k];
  __syncthreads();
  if (tid == 0) {
    int run = 0;
    for (int kk = 0; kk < NBK; ++kk) {
      base[kk] = run;
      int t = 0;
      for (int cc = 0; cc < CHUNKS; ++cc) t += arr[cc][kk];
      run += t;
    }
    base[NBK] = run;
  }
  __syncthreads();
  int pre = 0;
  for (int cc = 0; cc < c; ++cc) pre += arr[cc][k];
  cursor[((b * CHUNKS + c) << 4) + k] = base[k] + pre;
  if (tid < NBK + 1) bbase[b * (NBK + 1) + tid] = base[tid];
}

__global__ __launch_bounds__(256) void bin_scatter(const int* __restrict__ ei,
                                                   const int* __restrict__ cursor,
                                                   unsigned* __restrict__ pbuf) {
  int blk = blockIdx.x;
  int b = blk >> 4, c = blk & 15;
  __shared__ int gcur[NBK], lcnt[NBK], lfill[NBK];
  __shared__ int lbase[NBK + 1];
  __shared__ unsigned sbuf[2048];
  int tid = threadIdx.x;
  if (tid < NBK) gcur[tid] = cursor[(blk << 4) + tid];
  const int* srcp = ei + (size_t)b * 2 * E + c * 8192;
  const int* dstp = srcp + E;
  unsigned* pb = pbuf + (size_t)b * E;

  for (int sc = 0; sc < 4; ++sc) {
    if (tid < NBK) { lcnt[tid] = 0; lfill[tid] = 0; }
    __syncthreads();
    int s8[8], d8[8];
#pragma unroll
    for (int q = 0; q < 8; ++q) {
      int i = sc * 2048 + q * 256 + tid;
      s8[q] = srcp[i]; d8[q] = dstp[i];
      atomicAdd(&lcnt[d8[q] >> 9], 1);
    }
    __syncthreads();
    if (tid == 0) {
      int run = 0;
      for (int k = 0; k < NBK; ++k) { lbase[k] = run; run += lcnt[k]; }
      lbase[NBK] = run;
    }
    __syncthreads();
#pragma unroll
    for (int q = 0; q < 8; ++q) {
      int k = d8[q] >> 9;
      int idx = atomicAdd(&lfill[k], 1);
      sbuf[lbase[k] + idx] = ((unsigned)k << 22) |
                             ((unsigned)(d8[q] & 511) << 13) | (unsigned)s8[q];
    }
    __syncthreads();
    for (int i = tid; i < 2048; i += 256) {
      unsigned pk = sbuf[i];
      int k = (int)(pk >> 22);
      pb[gcur[k] + (i - lbase[k])] = pk;
    }
    __syncthreads();
    if (tid < NBK) gcur[tid] += lcnt[tid];
    __syncthreads();
  }
}

__global__ __launch_bounds__(256) void final_scatter(const unsigned* __restrict__ pbuf,
                                                     const int* __restrict__ bbase,
                                                     int* __restrict__ csr,
                                                     int* __restrict__ offs,
                                                     float* __restrict__ dinv1) {
  int blk = blockIdx.x;
  int b = blk >> 4, k = blk & 15;
  __shared__ int ncnt[512], nbase[512], nfill[512];
  __shared__ int sred[256];
  __shared__ unsigned sbuf[FCAP];
  int tid = threadIdx.x;
  int gbase = bbase[b * (NBK + 1) + k];
  int gend  = bbase[b * (NBK + 1) + k + 1];
  int cnt = gend - gbase;
  const unsigned* pb = pbuf + (size_t)b * E + gbase;

  for (int i = tid; i < 512; i += 256) { ncnt[i] = 0; nfill[i] = 0; }
  __syncthreads();
  for (int i = tid; i < cnt; i += 256) atomicAdd(&ncnt[(pb[i] >> 13) & 511], 1);
  __syncthreads();
  int v0 = ncnt[2 * tid], v1 = ncnt[2 * tid + 1];
  int s = v0 + v1;
  sred[tid] = s;
  __syncthreads();
  for (int off = 1; off < 256; off <<= 1) {
    int x = (tid >= off) ? sred[tid - off] : 0;
    __syncthreads();
    sred[tid] += x;
    __syncthreads();
  }
  int ex = sred[tid] - s;
  nbase[2 * tid] = ex;
  nbase[2 * tid + 1] = ex + v0;
  __syncthreads();
  for (int i = tid; i < 512; i += 256) {
    int node = k * 512 + i;
    offs[b * (N + 1) + node] = gbase + nbase[i];
    dinv1[b * N + node] = rsqrtf((float)ncnt[i] + 1.0f);
  }
  if (k == 15 && tid == 0) offs[b * (N + 1) + N] = E;
  __syncthreads();
  for (int i = tid; i < cnt; i += 256) {
    unsigned pk = pb[i];
    int node = (pk >> 13) & 511;
    int idx = atomicAdd(&nfill[node], 1);
    sbuf[nbase[node] + idx] = pk & 8191u;
  }
  __syncthreads();
  int* co = csr + (size_t)b * E + gbase;
  for (int i = tid; i < cnt; i += 256) co[i] = (int)sbuf[i];
}

// ---------------------------------------------------------------------------
// GEMM layer-1: full rows, fp32 A, dscale (=dinv1) in epilogue.
// ---------------------------------------------------------------------------
__global__ __launch_bounds__(256) void gemm_l1(const float* __restrict__ Ap,
                                               const unsigned short* __restrict__ Wt,
                                               unsigned short* __restrict__ Cb,
                                               const float* __restrict__ dscale) {
  __shared__ unsigned short Wsh[128 * 128];
  int tid  = threadIdx.x;
  int lane = tid & 63;
  int l15  = lane & 15, lg = lane >> 4;
  size_t rowbase = (size_t)blockIdx.x * 128 + (tid >> 6) * 32;

#pragma unroll
  for (int i = 0; i < 8; ++i) {
    int idx = tid + i * 256;
    int row = idx >> 4, s = idx & 15;
    short8 v = *(const short8*)(Wt + idx * 8);
    *(short8*)(Wsh + row * 128 + (s ^ (row & 15)) * 8) = v;
  }

  short8 afrag[2][4];
#pragma unroll
  for (int rg = 0; rg < 2; ++rg) {
    size_t row = rowbase + rg * 16 + l15;
#pragma unroll
    for (int c = 0; c < 4; ++c) {
      const float* p = Ap + row * 128 + c * 32 + lg * 8;
      float4 v0 = *(const float4*)p;
      float4 v1 = *(const float4*)(p + 4);
      short8 a;
      a[0] = (short)f2bf(v0.x); a[1] = (short)f2bf(v0.y);
      a[2] = (short)f2bf(v0.z); a[3] = (short)f2bf(v0.w);
      a[4] = (short)f2bf(v1.x); a[5] = (short)f2bf(v1.y);
      a[6] = (short)f2bf(v1.z); a[7] = (short)f2bf(v1.w);
      afrag[rg][c] = a;
    }
  }

  float fsr0[4], fsr1[4];
  {
    float4 t0 = *(const float4*)(dscale + rowbase + lg * 4);
    float4 t1 = *(const float4*)(dscale + rowbase + 16 + lg * 4);
    fsr0[0] = t0.x; fsr0[1] = t0.y; fsr0[2] = t0.z; fsr0[3] = t0.w;
    fsr1[0] = t1.x; fsr1[1] = t1.y; fsr1[2] = t1.z; fsr1[3] = t1.w;
  }

  __syncthreads();

#pragma unroll
  for (int t = 0; t < 8; ++t) {
    int col = t * 16 + l15;
    short8 bfrag[4];
#pragma unroll
    for (int c = 0; c < 4; ++c)
      bfrag[c] = *(const short8*)(Wsh + col * 128 + ((c * 4 + lg) ^ (col & 15)) * 8);

    floatx4 acc0 = {0.f, 0.f, 0.f, 0.f};
    floatx4 acc1 = {0.f, 0.f, 0.f, 0.f};
#pragma unroll
    for (int c = 0; c < 4; ++c) {
      acc0 = __builtin_amdgcn_mfma_f32_16x16x32_bf16(afrag[0][c], bfrag[c], acc0, 0, 0, 0);
      acc1 = __builtin_amdgcn_mfma_f32_16x16x32_bf16(afrag[1][c], bfrag[c], acc1, 0, 0, 0);
    }
#pragma unroll
    for (int r = 0; r < 4; ++r) {
      size_t row0 = rowbase + lg * 4 + r;
      size_t row1 = rowbase + 16 + lg * 4 + r;
      Cb[row0 * 128 + col] = f2bf(acc0[r] * fsr0[r]);
      Cb[row1 * 128 + col] = f2bf(acc1[r] * fsr1[r]);
    }
  }
}

// ---------------------------------------------------------------------------
// GEMM layers 2/3: LIVE rows only via per-graph index list.
// ---------------------------------------------------------------------------
template <int LGB>
__global__ __launch_bounds__(256) void gemm_idx(const unsigned short* __restrict__ Ab,
                                                const unsigned short* __restrict__ Wt,
                                                unsigned short* __restrict__ Cb,
                                                const float* __restrict__ fscale,
                                                const float* __restrict__ dscale,
                                                const int* __restrict__ idxl) {
  __shared__ unsigned short Wsh[128 * 128];
  __shared__ int ridx[128];
  int tid  = threadIdx.x;
  int lane = tid & 63;
  int l15  = lane & 15, lg = lane >> 4;
  int b    = blockIdx.x >> LGB;
  int lblk = blockIdx.x & ((1 << LGB) - 1);
  int woff = (tid >> 6) * 32;

  if (tid < 128) ridx[tid] = idxl[b * N + lblk * 128 + tid];
#pragma unroll
  for (int i = 0; i < 8; ++i) {
    int idx = tid + i * 256;
    int row = idx >> 4, s = idx & 15;
    short8 v = *(const short8*)(Wt + idx * 8);
    *(short8*)(Wsh + row * 128 + (s ^ (row & 15)) * 8) = v;
  }
  __syncthreads();

  const unsigned short* Ag = Ab + (size_t)b * N * 128;
  unsigned short* Cg = Cb + (size_t)b * N * 128;
  const float* fsb = fscale + b * N;
  const float* dsb = dscale + b * N;

  short8 afrag[2][4];
#pragma unroll
  for (int rg = 0; rg < 2; ++rg) {
    int arow = ridx[woff + rg * 16 + l15];
#pragma unroll
    for (int c = 0; c < 4; ++c)
      afrag[rg][c] = *(const short8*)(Ag + (size_t)arow * 128 + c * 32 + lg * 8);
  }

  int orow[2][4]; float fsr[2][4];
#pragma unroll
  for (int rg = 0; rg < 2; ++rg)
#pragma unroll
    for (int r = 0; r < 4; ++r) {
      int o = ridx[woff + rg * 16 + lg * 4 + r];
      orow[rg][r] = o;
      fsr[rg][r] = fsb[o] * dsb[o];
    }

#pragma unroll
  for (int t = 0; t < 8; ++t) {
    int col = t * 16 + l15;
    short8 bfrag[4];
#pragma unroll
    for (int c = 0; c < 4; ++c)
      bfrag[c] = *(const short8*)(Wsh + col * 128 + ((c * 4 + lg) ^ (col & 15)) * 8);

    floatx4 acc0 = {0.f, 0.f, 0.f, 0.f};
    floatx4 acc1 = {0.f, 0.f, 0.f, 0.f};
#pragma unroll
    for (int c = 0; c < 4; ++c) {
      acc0 = __builtin_amdgcn_mfma_f32_16x16x32_bf16(afrag[0][c], bfrag[c], acc0, 0, 0, 0);
      acc1 = __builtin_amdgcn_mfma_f32_16x16x32_bf16(afrag[1][c], bfrag[c], acc1, 0, 0, 0);
    }
#pragma unroll
    for (int r = 0; r < 4; ++r) {
      Cg[(size_t)orow[0][r] * 128 + col] = f2bf(acc0[r] * fsr[0][r]);
      Cg[(size_t)orow[1][r] * 128 + col] = f2bf(acc1[r] * fsr[1][r]);
    }
  }
}

// ---------------------------------------------------------------------------
// GCN aggregation layer-1 (full, all live) — proven agg8 structure.
// ---------------------------------------------------------------------------
__global__ __launch_bounds__(256) void gcn_agg_l1(
    const unsigned* __restrict__ tmp, const float* __restrict__ dinv,
    const int* __restrict__ offs, const int* __restrict__ csr,
    const float* __restrict__ bias, unsigned* __restrict__ hout,
    const float* __restrict__ wrel, const float* __restrict__ wroot,
    float* __restrict__ rr, float* __restrict__ tt) {
  int blk = blockIdx.x;
  int xcd = blk & 7;
  int j   = blk >> 3;
  int b   = xcd + 8 * (j >> 11);
  int n   = (j & 2047) * 4 + (threadIdx.x >> 6);
  int wid = b * N + n;
  int lane = threadIdx.x & 63;

  float dv = rdlane_f(dinv[wid], 0);
  unsigned* hrow = hout + (size_t)wid * 64;

  const unsigned* tmpb = tmp + (((size_t)b << 13) << 6);
  const int* cs = csr + (size_t)b * E;

  float2 accA, accB;
  {
    unsigned u = tmpb[((unsigned)n << 6) + lane];
    accA.x = __uint_as_float(u << 16);
    accA.y = __uint_as_float(u & 0xFFFF0000u);
    accB.x = 0.0f; accB.y = 0.0f;
  }

  int nbase = b * (N + 1) + n;
  int o0 = __builtin_amdgcn_readfirstlane(offs[nbase]);
  int d  = __builtin_amdgcn_readfirstlane(offs[nbase + 1]) - o0;

  for (int base = 0; base < d; base += 64) {
    int nv = d - base; if (nv > 64) nv = 64;
    int sl = (lane < nv) ? cs[o0 + base + lane] : 0;
    int nfull = nv >> 4;
    for (int t = 0; t < nfull; ++t) {
      int i0 = t << 4;
      unsigned uu[16];
#pragma unroll
      for (int q = 0; q < 16; ++q) {
        int sq = rdlane_i(sl, i0 + q);
        uu[q] = tmpb[((unsigned)sq << 6) + lane];
      }
#pragma unroll
      for (int q = 0; q < 16; ++q) {
        float lo = __uint_as_float(uu[q] << 16);
        float hi = __uint_as_float(uu[q] & 0xFFFF0000u);
        if (q & 1) { accB.x += lo; accB.y += hi; }
        else       { accA.x += lo; accA.y += hi; }
      }
    }
    int rem = nv & 15;
    if (rem) {
      int i0 = nfull << 4;
      unsigned uu[16];
#pragma unroll
      for (int q = 0; q < 16; ++q) {
        int idx = i0 + q;
        int sq = rdlane_i(sl, idx < nv ? idx : 0);
        unsigned v = tmpb[((unsigned)sq << 6) + lane];
        uu[q] = (idx < nv) ? v : 0u;
      }
#pragma unroll
      for (int q = 0; q < 16; ++q) {
        float lo = __uint_as_float(uu[q] << 16);
        float hi = __uint_as_float(uu[q] & 0xFFFF0000u);
        if (q & 1) { accB.x += lo; accB.y += hi; }
        else       { accA.x += lo; accA.y += hi; }
      }
    }
  }

  float2 acc = {accA.x + accB.x, accA.y + accB.y};
  const float2 bb = *(const float2*)(bias + lane * 2);
  float2 outv;
  outv.x = fmaxf(dv * acc.x + bb.x, 0.0f);
  outv.y = fmaxf(dv * acc.y + bb.y, 0.0f);
  hrow[lane] = cvt_pk_bf16(outv.x, outv.y);

  const float2 wr = *(const float2*)(wrel + lane * 2);
  const float2 wo = *(const float2*)(wroot + lane * 2);
  float pr = outv.x * wr.x + outv.y * wr.y;
  float pt = outv.x * wo.x + outv.y * wo.y;
#pragma unroll
  for (int dd = 32; dd > 0; dd >>= 1) {
    pr += __shfl_down(pr, dd);
    pt += __shfl_down(pt, dd);
  }
  if (lane == 0) { rr[wid] = pr; tt[wid] = pt; }
}

// ---------------------------------------------------------------------------
// GCN aggregation layers 2/3 (live index list). FUSE_RO: fused readout.
// ---------------------------------------------------------------------------
template <int LOGPG, bool FUSE_RO>
__global__ __launch_bounds__(256) void gcn_agg_idx(
    const unsigned* __restrict__ tmp, const float* __restrict__ dinv,
    const int* __restrict__ offs, const int* __restrict__ ecnt,
    const int* __restrict__ csr, const float* __restrict__ bias,
    unsigned* __restrict__ hout, const float* __restrict__ wrel,
    const float* __restrict__ wroot, float* __restrict__ rr,
    float* __restrict__ tt, const int* __restrict__ idxl,
    float* __restrict__ gacc) {
  __shared__ float racc[128];
  int blk = blockIdx.x;
  int xcd = blk & 7;
  int j   = blk >> 3;
  int b   = xcd + 8 * (j >> LOGPG);
  int i   = (j & ((1 << LOGPG) - 1)) * 4 + (threadIdx.x >> 6);
  int lane = threadIdx.x & 63;

  if (FUSE_RO) {
    if (threadIdx.x < 128) racc[threadIdx.x] = 0.0f;
    __syncthreads();
  }

  int n = __builtin_amdgcn_readfirstlane(idxl[b * N + i]);
  int wid = b * N + n;
  float dv = rdlane_f(dinv[wid], 0);

  const unsigned* tmpb = tmp + (((size_t)b << 13) << 6);
  const int* cs = csr + (size_t)b * E;

  float2 accA, accB;
  {
    unsigned u = tmpb[((unsigned)n << 6) + lane];
    accA.x = __uint_as_float(u << 16);
    accA.y = __uint_as_float(u & 0xFFFF0000u);
    accB.x = 0.0f; accB.y = 0.0f;
  }

  int o0 = __builtin_amdgcn_readfirstlane(offs[b * (N + 1) + n]);
  int d  = __builtin_amdgcn_readfirstlane(ecnt[wid]);

  for (int base = 0; base < d; base += 64) {
    int nv = d - base; if (nv > 64) nv = 64;
    int sl = (lane < nv) ? cs[o0 + base + lane] : 0;
    int nfull = nv >> 4;
    for (int t = 0; t < nfull; ++t) {
      int i0 = t << 4;
      unsigned uu[16];
#pragma unroll
      for (int q = 0; q < 16; ++q) {
        int sq = rdlane_i(sl, i0 + q);
        uu[q] = tmpb[((unsigned)sq << 6) + lane];
      }
#pragma unroll
      for (int q = 0; q < 16; ++q) {
        float lo = __uint_as_float(uu[q] << 16);
        float hi = __uint_as_float(uu[q] & 0xFFFF0000u);
        if (q & 1) { accB.x += lo; accB.y += hi; }
        else       { accA.x += lo; accA.y += hi; }
      }
    }
    int rem = nv & 15;
    if (rem) {
      int i0 = nfull << 4;
      unsigned uu[16];
#pragma unroll
      for (int q = 0; q < 16; ++q) {
        int idx = i0 + q;
        int sq = rdlane_i(sl, idx < nv ? idx : 0);
        unsigned v = tmpb[((unsigned)sq << 6) + lane];
        uu[q] = (idx < nv) ? v : 0u;
      }
#pragma unroll
      for (int q = 0; q < 16; ++q) {
        float lo = __uint_as_float(uu[q] << 16);
        float hi = __uint_as_float(uu[q] & 0xFFFF0000u);
        if (q & 1) { accB.x += lo; accB.y += hi; }
        else       { accA.x += lo; accA.y += hi; }
      }
    }
  }

  float2 acc = {accA.x + accB.x, accA.y + accB.y};
  const float2 bb = *(const float2*)(bias + lane * 2);
  float2 outv;
  outv.x = fmaxf(dv * acc.x + bb.x, 0.0f);
  outv.y = fmaxf(dv * acc.y + bb.y, 0.0f);

  if (!FUSE_RO) {
    unsigned* hrow = hout + (size_t)wid * 64;
    hrow[lane] = cvt_pk_bf16(outv.x, outv.y);
    const float2 wr = *(const float2*)(wrel + lane * 2);
    const float2 wo = *(const float2*)(wroot + lane * 2);
    float pr = outv.x * wr.x + outv.y * wr.y;
    float pt = outv.x * wo.x + outv.y * wo.y;
#pragma unroll
    for (int dd = 32; dd > 0; dd >>= 1) {
      pr += __shfl_down(pr, dd);
      pt += __shfl_down(pt, dd);
    }
    if (lane == 0) { rr[wid] = pr; tt[wid] = pt; }
  } else {
    atomicAdd(&racc[lane * 2],     outv.x);
    atomicAdd(&racc[lane * 2 + 1], outv.y);
    __syncthreads();
    if (threadIdx.x < 128) atomicAdd(&gacc[b * 128 + threadIdx.x], racc[threadIdx.x]);
  }
}

// ---------------------------------------------------------------------------
// compact (live nodes only, via index list)
// ---------------------------------------------------------------------------
template <int LOGK>
__global__ __launch_bounds__(256) void compact_idx(
    const int* __restrict__ idxl, const float* __restrict__ mask,
    const int* __restrict__ offs, const int* __restrict__ ecnt_in,
    int* __restrict__ csr, int* __restrict__ ecnt_out,
    float* __restrict__ dinv_out) {
  int ws = blockIdx.x * 4 + (threadIdx.x >> 6);
  int b = ws >> LOGK;
  int i = ws & ((1 << LOGK) - 1);
  int lane = threadIdx.x & 63;
  int n = __builtin_amdgcn_readfirstlane(idxl[b * N + i]);
  int wid = b * N + n;
  int nb = b * (N + 1) + n;
  int o0 = __builtin_amdgcn_readfirstlane(offs[nb]);
  int din = (ecnt_in != nullptr)
                ? __builtin_amdgcn_readfirstlane(ecnt_in[wid])
                : __builtin_amdgcn_readfirstlane(offs[nb + 1]) - o0;
  int* cs = csr + (size_t)b * E;
  const float* mb = mask + b * N;
  int wpos = o0;
  for (int base = 0; base < din; base += 64) {
    int nv = din - base; if (nv > 64) nv = 64;
    int s = (lane < nv) ? cs[o0 + base + lane] : 0;
    bool alive = (lane < nv) && (mb[s] > 0.0f);
    unsigned long long bal = __ballot(alive);
    int idx = __popcll(bal & ((1ull << lane) - 1ull));
    if (alive) cs[wpos + idx] = s;
    wpos += __popcll(bal);
  }
  if (lane == 0) {
    int total = wpos - o0;
    ecnt_out[wid] = total;
    dinv_out[wid] = rsqrtf((float)total + 1.0f);
  }
}

// ---------------------------------------------------------------------------
// pool score layer 1 (full) and layer 2 (idx-restricted)
// ---------------------------------------------------------------------------
__global__ __launch_bounds__(256) void score_l1(const float* __restrict__ r,
                                                const float* __restrict__ t,
                                                const float* __restrict__ pb,
                                                const int* __restrict__ offs,
                                                const int* __restrict__ csr,
                                                float* __restrict__ score) {
  int grp = threadIdx.x >> 4;
  int gl  = threadIdx.x & 15;
  int nid = blockIdx.x * 16 + grp;
  int b = nid >> 13, n = nid & (N - 1);
  int o0 = offs[b * (N + 1) + n], o1 = offs[b * (N + 1) + n + 1];
  const int* cs = csr + (size_t)b * E;
  const float* rb = r + b * N;
  float s = 0.0f;
  for (int base = o0; base < o1; base += 16)
    if (base + gl < o1) s += rb[cs[base + gl]];
#pragma unroll
  for (int dd = 8; dd > 0; dd >>= 1) s += __shfl_xor(s, dd, 16);
  if (gl == 0) score[nid] = s + t[nid] + pb[0];
}

__global__ __launch_bounds__(256) void score_idx(const float* __restrict__ r,
                                                 const float* __restrict__ t,
                                                 const float* __restrict__ pb,
                                                 const int* __restrict__ offs,
                                                 const int* __restrict__ ecnt,
                                                 const int* __restrict__ csr,
                                                 float* __restrict__ score,
                                                 const int* __restrict__ idxl) {
  int grp = threadIdx.x >> 4;
  int gl  = threadIdx.x & 15;
  int ws  = blockIdx.x * 16 + grp;
  int b = ws >> 12;
  int i = ws & (K1 - 1);
  int n = idxl[b * N + i];
  int nid = b * N + n;
  int o0 = offs[b * (N + 1) + n];
  int d  = ecnt[nid];
  const int* cs = csr + (size_t)b * E;
  const float* rb = r + b * N;
  float s = 0.0f;
  for (int base = 0; base < d; base += 16)
    if (base + gl < d) s += rb[cs[o0 + base + gl]];
#pragma unroll
  for (int dd = 8; dd > 0; dd >>= 1) s += __shfl_xor(s, dd, 16);
  if (gl == 0) score[nid] = s + t[nid] + pb[0];
}

// ---------------------------------------------------------------------------
// top-k via radix select + compacted index emission
// ---------------------------------------------------------------------------
__device__ __forceinline__ unsigned fkey(float s, float m) {
  if (m <= 0.0f) return 0u;
  unsigned u = __float_as_uint(s);
  return (u & 0x80000000u) ? ~u : (u | 0x80000000u);
}

__global__ __launch_bounds__(1024) void topk_kernel(const float* __restrict__ score,
                                                    const float* __restrict__ mkin,
                                                    float* __restrict__ mkout,
                                                    float* __restrict__ fscale,
                                                    int* __restrict__ idxo,
                                                    int k) {
  int b = blockIdx.x, tid = threadIdx.x;
  const float* sc = score + b * N;
  float* mk = mkout + b * N;
  float* fs = fscale + b * N;
  __shared__ unsigned keyb[N];
  __shared__ int hist[256];
  __shared__ unsigned sh_prefix;
  __shared__ int sh_kneed;
  __shared__ int wsum[16], wexc[16];

  for (int i = tid; i < N; i += 1024) {
    float m = (mkin == nullptr) ? 1.0f : mkin[b * N + i];
    keyb[i] = fkey(sc[i], m);
  }
  __syncthreads();

  unsigned prefix = 0, hm = 0;
  int kneed = k;
  for (int shift = 24; shift >= 0; shift -= 8) {
    if (tid < 256) hist[tid] = 0;
    __syncthreads();
    for (int i = tid; i < N; i += 1024) {
      unsigned key = keyb[i];
      if ((key & hm) == prefix) atomicAdd(&hist[(key >> shift) & 255], 1);
    }
    __syncthreads();
    if (tid < 64) {
      int b4[4]; int s = 0;
#pragma unroll
      for (int j = 0; j < 4; ++j) { b4[j] = hist[tid * 4 + j]; s += b4[j]; }
      int suf = s;
#pragma unroll
      for (int o = 1; o < 64; o <<= 1) {
        int v = __shfl_down(suf, o);
        if (tid + o < 64) suf += v;
      }
      int run = suf - s;
      for (int j = 3; j >= 0; --j) {
        if (run < kneed && run + b4[j] >= kneed) {
          sh_prefix = prefix | ((unsigned)(tid * 4 + j) << shift);
          sh_kneed = kneed - run;
        }
        run += b4[j];
      }
    }
    __syncthreads();
    prefix = sh_prefix;
    kneed = sh_kneed;
    hm |= (0xFFu << shift);
  }

  unsigned T = prefix;
  int base = tid * 8;
  unsigned keys[8];
  int eqf[8];
  int cnt = 0;
#pragma unroll
  for (int q = 0; q < 8; ++q) {
    keys[q] = keyb[base + q];
    eqf[q] = (keys[q] == T) ? 1 : 0;
    cnt += eqf[q];
  }
  int inc = cnt;
  int wl = tid & 63;
#pragma unroll
  for (int o = 1; o < 64; o <<= 1) {
    int v = __shfl_up(inc, o);
    if (wl >= o) inc += v;
  }
  if (wl == 63) wsum[tid >> 6] = inc;
  __syncthreads();
  if (tid < 16) {
    int v = wsum[tid];
    int in = v;
#pragma unroll
    for (int o = 1; o < 16; o <<= 1) {
      int u = __shfl_up(in, o);
      if (tid >= o) in += u;
    }
    wexc[tid] = in - v;
  }
  __syncthreads();
  int ex = wexc[tid >> 6] + (inc - cnt);
  int scnt = 0; bool selq[8];
#pragma unroll
  for (int q = 0; q < 8; ++q) {
    bool sel = (keys[q] > T) || (eqf[q] && (ex < kneed));
    ex += eqf[q];
    mk[base + q] = sel ? 1.0f : 0.0f;
    fs[base + q] = sel ? tanhf(sc[base + q]) : 0.0f;
    selq[q] = sel; scnt += sel;
  }
  int inc2 = scnt;
#pragma unroll
  for (int o = 1; o < 64; o <<= 1) {
    int v = __shfl_up(inc2, o);
    if (wl >= o) inc2 += v;
  }
  __syncthreads();
  if (wl == 63) wsum[tid >> 6] = inc2;
  __syncthreads();
  if (tid < 16) {
    int v = wsum[tid];
    int in = v;
#pragma unroll
    for (int o = 1; o < 16; o <<= 1) {
      int u = __shfl_up(in, o);
      if (tid >= o) in += u;
    }
    wexc[tid] = in - v;
  }
  __syncthreads();
  int spos = wexc[tid >> 6] + (inc2 - scnt);
  int* io = idxo + b * N;
#pragma unroll
  for (int q = 0; q < 8; ++q)
    if (selq[q]) io[spos++] = base + q;
}

// ---------------------------------------------------------------------------
// head MLP + log_softmax
// ---------------------------------------------------------------------------
__global__ __launch_bounds__(128) void head(const float* __restrict__ gacc,
                                            const float* __restrict__ l1w,
                                            const float* __restrict__ l1b,
                                            const float* __restrict__ l2w,
                                            const float* __restrict__ l2b,
                                            float* __restrict__ out) {
  int b = blockIdx.x, f = threadIdx.x;
  float g = gacc[b * 128 + f] * (1.0f / (float)K2);
  __shared__ float gs[128], hh[128], lg[10];
  gs[f] = g; __syncthreads();
  float a = l1b[f];
  for (int kk = 0; kk < 128; ++kk) a += gs[kk] * l1w[kk * 128 + f];
  hh[f] = fmaxf(a, 0.0f); __syncthreads();
  if (f < 10) {
    float l = l2b[f];
    for (int j = 0; j < 128; ++j) l += hh[j] * l2w[j * 10 + f];
    lg[f] = l;
  }
  __syncthreads();
  if (f == 0) {
    float m = lg[0];
    for (int c = 1; c < 10; ++c) m = fmaxf(m, lg[c]);
    float s = 0.0f;
    for (int c = 0; c < 10; ++c) s += expf(lg[c] - m);
    float lse = m + logf(s);
    for (int c = 0; c < 10; ++c) out[b * 10 + c] = lg[c] - lse;
  }
}

// ---------------------------------------------------------------------------
extern "C" void kernel_launch(void* const* d_in, const int* in_sizes, int n_in,
                              void* d_out, int out_size, void* d_ws, size_t ws_size,
                              hipStream_t stream) {
  (void)in_sizes; (void)n_in; (void)out_size; (void)ws_size;
  const float* x       = (const float*)d_in[0];
  const int*   ei      = (const int*)d_in[1];
  const float* W1      = (const float*)d_in[2];
  const float* b1      = (const float*)d_in[3];
  const float* p1_wrel = (const float*)d_in[4];
  const float* p1_wroot= (const float*)d_in[5];
  const float* p1_b    = (const float*)d_in[6];
  const float* W2      = (const float*)d_in[7];
  const float* b2      = (const float*)d_in[8];
  const float* p2_wrel = (const float*)d_in[9];
  const float* p2_wroot= (const float*)d_in[10];
  const float* p2_b    = (const float*)d_in[11];
  const float* W3      = (const float*)d_in[12];
  const float* b3      = (const float*)d_in[13];
  const float* l1w     = (const float*)d_in[14];
  const float* l1b     = (const float*)d_in[15];
  const float* l2w     = (const float*)d_in[16];
  const float* l2b     = (const float*)d_in[17];
  float* out = (float*)d_out;

  char* p = (char*)d_ws;
  auto alloc = [&](size_t bytes) {
    char* r = p;
    p += ((bytes + 255) & ~(size_t)255);
    return r;
  };
  unsigned short* h   = (unsigned short*)alloc((size_t)B * N * H * 2);   // bf16
  unsigned short* tmp = (unsigned short*)alloc((size_t)B * N * H * 2);   // bf16
  int*      offs   = (int*)alloc((size_t)B * (N + 1) * 4);
  int*      csr    = (int*)alloc((size_t)B * E * 4);
  unsigned* pbuf   = (unsigned*)alloc((size_t)B * E * 4);
  int*      bchist = (int*)alloc((size_t)B * CHUNKS * NBK * 4);
  int*      cursor = (int*)alloc((size_t)B * CHUNKS * NBK * 4);
  int*      bbase  = (int*)alloc((size_t)B * (NBK + 1) * 4);
  int*      ecnt   = (int*)alloc((size_t)B * N * 4);
  int*      idx1   = (int*)alloc((size_t)B * N * 4);
  int*      idx2   = (int*)alloc((size_t)B * N * 4);
  float* dinv   = (float*)alloc((size_t)B * N * 4);
  float* mask   = (float*)alloc((size_t)B * N * 4);
  float* rr     = (float*)alloc((size_t)B * N * 4);
  float* tt     = (float*)alloc((size_t)B * N * 4);
  float* score  = (float*)alloc((size_t)B * N * 4);
  float* fscale = (float*)alloc((size_t)B * N * 4);
  float* gacc   = (float*)alloc((size_t)B * 128 * 4);
  unsigned short* Wts = (unsigned short*)alloc(3 * 128 * 128 * 2);

  // CSR build + weight prep + gacc zeroing (fused)
  hist_pass<<<B * CHUNKS, 256, 0, stream>>>(ei, bchist);
  bucket_scan<<<19, 256, 0, stream>>>(bchist, cursor, bbase, W1, W2, W3, Wts, gacc);
  bin_scatter<<<B * CHUNKS, 256, 0, stream>>>(ei, cursor, pbuf);
  final_scatter<<<B * NBK, 256, 0, stream>>>(pbuf, bbase, csr, offs, dinv);

  // ---- layer 1 + pool 1 (all nodes live)
  gemm_l1<<<(B * N) / 128, 256, 0, stream>>>(x, Wts, tmp, dinv);
  gcn_agg_l1<<<B * N / 4, 256, 0, stream>>>((const unsigned*)tmp, dinv, offs, csr, b1,
                                            (unsigned*)h, p1_wrel, p1_wroot, rr, tt);
  score_l1<<<B * N / 16, 256, 0, stream>>>(rr, tt, p1_b, offs, csr, score);
  topk_kernel<<<B, 1024, 0, stream>>>(score, nullptr, mask, fscale, idx1, K1);
  compact_idx<12><<<B * K1 / 4, 256, 0, stream>>>(idx1, mask, offs, nullptr, csr,
                                                  ecnt, dinv);

  // ---- layer 2 + pool 2 (live subgraph via idx1)
  gemm_idx<5><<<B * (K1 / 128), 256, 0, stream>>>(h, Wts + 128 * 128, tmp,
                                                  fscale, dinv, idx1);
  gcn_agg_idx<10, false><<<B * K1 / 4, 256, 0, stream>>>(
      (const unsigned*)tmp, dinv, offs, ecnt, csr, b2, (unsigned*)h,
      p2_wrel, p2_wroot, rr, tt, idx1, nullptr);
  score_idx<<<B * K1 / 16, 256, 0, stream>>>(rr, tt, p2_b, offs, ecnt, csr,
                                             score, idx1);
  topk_kernel<<<B, 1024, 0, stream>>>(score, mask, mask, fscale, idx2, K2);
  compact_idx<11><<<B * K2 / 4, 256, 0, stream>>>(idx2, mask, offs, ecnt, csr,
                                                  ecnt, dinv);

  // ---- layer 3 (live subgraph via idx2; fused readout)
  gemm_idx<4><<<B * (K2 / 128), 256, 0, stream>>>(h, Wts + 2 * 128 * 128, tmp,
                                                  fscale, dinv, idx2);
  gcn_agg_idx<9, true><<<B * K2 / 4, 256, 0, stream>>>(
      (const unsigned*)tmp, dinv, offs, ecnt, csr, b3, nullptr,
      nullptr, nullptr, nullptr, nullptr, idx2, gacc);

  // ---- head
  head<<<B, 128, 0, stream>>>(gacc, l1w, l1b, l2w, l2b, out);
}